// Round 6
// baseline (326.118 us; speedup 1.0000x reference)
//
#include <hip/hip_runtime.h>
#include <hip/hip_bf16.h>
#include <stdint.h>

#define T_TOK 2048
#define DMODEL 1024
#define FDIM 2048
#define NEXP 8
#define MAXS 40   // sum ceil(c_e/128) <= 4096/128 + 8 = 40

typedef __bf16 bf16;
typedef __attribute__((ext_vector_type(8))) __bf16 bf16x8;
typedef __attribute__((ext_vector_type(4))) float f32x4;

#define GLOBAL_AS __attribute__((address_space(1)))
#define LDS_AS __attribute__((address_space(3)))
#define VMCNT(n) asm volatile("s_waitcnt vmcnt(" #n ")" ::: "memory")
#define GLD16(src, dst) __builtin_amdgcn_global_load_lds((const GLOBAL_AS void*)(src), (LDS_AS void*)(dst), 16, 0, 0)

// slab sizes in bf16 elements
#define XG_SLOT   131072u   // 32 kt * 4 kc * 128 rows * 8
#define H_SLOT    262144u   // 64 kt * 4 kc * 128 rows * 8
#define W_SLAB    2097152u  // per-expert blocked weight slab (D*F)

// ---------------- Router: fp32 logits, top-2, renormalized weights ----------------
__global__ __launch_bounds__(64) void moe_router(
    const float* __restrict__ x, const float* __restrict__ rw,
    bf16* __restrict__ xb, int* __restrict__ counts,
    int* __restrict__ tok_list, float* __restrict__ wgt_list)
{
  const int t = blockIdx.x;
  const int lane = threadIdx.x;
  const float* xr = x + (size_t)t * DMODEL;
  float acc[NEXP];
#pragma unroll
  for (int e = 0; e < NEXP; ++e) acc[e] = 0.f;
  for (int d = lane; d < DMODEL; d += 64) {
    float xv = xr[d];
    if (xb) xb[(size_t)t * DMODEL + d] = (bf16)xv;   // only for fallback path
    const float* r = rw + (size_t)d * NEXP;
#pragma unroll
    for (int e = 0; e < NEXP; ++e) acc[e] += xv * r[e];
  }
#pragma unroll
  for (int e = 0; e < NEXP; ++e) {
#pragma unroll
    for (int off = 32; off >= 1; off >>= 1)
      acc[e] += __shfl_xor(acc[e], off, 64);
  }
  if (lane == 0) {
    int i0 = 0; float m0 = acc[0];
#pragma unroll
    for (int e = 1; e < NEXP; ++e) { if (acc[e] > m0) { m0 = acc[e]; i0 = e; } }
    int i1 = -1; float m1 = -3.402823466e38f;
#pragma unroll
    for (int e = 0; e < NEXP; ++e) { if (e != i0 && acc[e] > m1) { m1 = acc[e]; i1 = e; } }
    float r = expf(m1 - m0);               // p1/p0; softmax denominator cancels
    float w0 = 1.f / (1.f + r);
    float w1v = r / (1.f + r);
    int p0 = atomicAdd(&counts[i0], 1);
    tok_list[i0 * T_TOK + p0] = t;
    wgt_list[i0 * T_TOK + p0] = w0;
    int p1 = atomicAdd(&counts[i1], 1);
    tok_list[i1 * T_TOK + p1] = t;
    wgt_list[i1 * T_TOK + p1] = w1v;
  }
}

// ---------------- Prefix + dense tile schedule ----------------
__global__ void moe_prefix(const int* __restrict__ counts, int* __restrict__ base,
                           int* __restrict__ sched)
{
  if (threadIdx.x == 0) {
    int s = 0, i = 0;
    for (int e = 0; e < NEXP; ++e) {
      base[e] = s; s += counts[e];
      const int nt = (counts[e] + 127) / 128;
      for (int tt = 0; tt < nt; ++tt) sched[i++] = (e << 16) | tt;
    }
    for (; i < MAXS; ++i) sched[i] = -1;
  }
}

// ---------------- Gather routed token rows into blocked Xg [slot][kt][kc][128][8] ----------------
__global__ __launch_bounds__(256) void moe_gather(
    const float* __restrict__ x, const int* __restrict__ tok_list,
    const int* __restrict__ counts, const int* __restrict__ sched,
    bf16* __restrict__ xg)
{
  const int s = sched[blockIdx.x];
  if (s < 0) return;
  const int e = s >> 16, tt = s & 0xffff;
  int rem = counts[e] - tt * 128; if (rem > 128) rem = 128;
  const int w = threadIdx.x >> 6, lane = threadIdx.x & 63;
  const int r = blockIdx.y * 4 + w;           // 0..127
  const int rc = r < rem ? r : rem - 1;
  const int tok = tok_list[e * T_TOK + tt * 128 + rc];
  const float* xr = x + (size_t)tok * DMODEL + lane * 16;   // 64B/lane, coalesced
  f32x4 v0 = *(const f32x4*)(xr);
  f32x4 v1 = *(const f32x4*)(xr + 4);
  f32x4 v2 = *(const f32x4*)(xr + 8);
  f32x4 v3 = *(const f32x4*)(xr + 12);
  bf16x8 a, b;
#pragma unroll
  for (int j = 0; j < 4; ++j) { a[j] = (bf16)v0[j]; a[4 + j] = (bf16)v1[j]; }
#pragma unroll
  for (int j = 0; j < 4; ++j) { b[j] = (bf16)v2[j]; b[4 + j] = (bf16)v3[j]; }
  // lane covers d = lane*16 .. +15 -> chunk indices (d/8) = 2*lane, 2*lane+1
  bf16* dst = xg + (size_t)blockIdx.x * XG_SLOT + (size_t)(lane * 2) * 1024 + r * 8;
  *(bf16x8*)dst = a;
  *(bf16x8*)(dst + 1024) = b;
}

// ---------------- Transpose + cvt into blocked weight layouts ----------------
// w1/w2 (D,F) -> [e][ft F/64][ktd D/32][kc 4][fi 64][j 8]
__global__ __launch_bounds__(256) void transpose_blk12(
    const float* __restrict__ w1, const float* __restrict__ w2,
    bf16* __restrict__ w1b, bf16* __restrict__ w2b)
{
  const int C = FDIM;
  __shared__ float tile[64][65];
  const int z = blockIdx.z;
  const int e = z & 7;
  const float* inp = (z < 8 ? w1 : w2) + (size_t)e * DMODEL * FDIM;
  bf16* outp = (z < 8 ? w1b : w2b) + (size_t)e * W_SLAB;
  const int rb = blockIdx.y * 64;   // over D
  const int cb = blockIdx.x * 64;   // over F
  const int tid = threadIdx.x;
  const int r = tid >> 2, c0 = (tid & 3) * 16;
  const float* src = inp + (size_t)(rb + r) * C + (cb + c0);
#pragma unroll
  for (int j = 0; j < 16; j += 4) {
    f32x4 v = *(const f32x4*)(src + j);
    tile[r][c0 + j + 0] = v[0];
    tile[r][c0 + j + 1] = v[1];
    tile[r][c0 + j + 2] = v[2];
    tile[r][c0 + j + 3] = v[3];
  }
  __syncthreads();
  // this thread outputs f-row (cb+r), d-range rb+c0 .. +15
  bf16x8 a, b;
#pragma unroll
  for (int j = 0; j < 8; ++j) a[j] = (bf16)tile[c0 + j][r];
#pragma unroll
  for (int j = 0; j < 8; ++j) b[j] = (bf16)tile[c0 + 8 + j][r];
  const int ft = blockIdx.x;                 // cb/64
  const int ktd = blockIdx.y * 2 + c0 / 32;  // (rb+c0)/32
  const int kc = (c0 & 31) / 8;              // 0 or 2
  bf16* dst = outp + ((size_t)ft * 128 + ktd * 4 + kc) * 512 + r * 8;
  *(bf16x8*)dst = a;
  *(bf16x8*)(dst + 512) = b;                 // kc+1
}

// w3 (F,D) -> [e][dt D/64][ktf F/32][kc 4][di 64][j 8]
__global__ __launch_bounds__(256) void transpose_blk3(
    const float* __restrict__ w3, bf16* __restrict__ w3b)
{
  const int C = DMODEL;
  __shared__ float tile[64][65];
  const int e = blockIdx.z;
  const float* inp = w3 + (size_t)e * FDIM * DMODEL;
  bf16* outp = w3b + (size_t)e * W_SLAB;
  const int rb = blockIdx.y * 64;   // over F
  const int cb = blockIdx.x * 64;   // over D
  const int tid = threadIdx.x;
  const int r = tid >> 2, c0 = (tid & 3) * 16;
  const float* src = inp + (size_t)(rb + r) * C + (cb + c0);
#pragma unroll
  for (int j = 0; j < 16; j += 4) {
    f32x4 v = *(const f32x4*)(src + j);
    tile[r][c0 + j + 0] = v[0];
    tile[r][c0 + j + 1] = v[1];
    tile[r][c0 + j + 2] = v[2];
    tile[r][c0 + j + 3] = v[3];
  }
  __syncthreads();
  // outputs d-row (cb+r), f-range rb+c0 .. +15
  bf16x8 a, b;
#pragma unroll
  for (int j = 0; j < 8; ++j) a[j] = (bf16)tile[c0 + j][r];
#pragma unroll
  for (int j = 0; j < 8; ++j) b[j] = (bf16)tile[c0 + 8 + j][r];
  const int dt = blockIdx.x;
  const int ktf = blockIdx.y * 2 + c0 / 32;
  const int kc = (c0 & 31) / 8;
  bf16* dst = outp + ((size_t)dt * 256 + ktf * 4 + kc) * 512 + r * 8;
  *(bf16x8*)dst = a;
  *(bf16x8*)(dst + 512) = b;
}

// ---------------- GEMM1: 128 tok x 128 F tile; H = silu(Xg@W1)*(Xg@W2) ----------------
__global__ __launch_bounds__(256) void moe_gemm1_blk(
    const bf16* __restrict__ xg,
    const bf16* __restrict__ w1b, const bf16* __restrict__ w2b,
    const int* __restrict__ counts, const int* __restrict__ sched,
    bf16* __restrict__ hblk)
{
  const int s = sched[blockIdx.y];
  if (s < 0) return;
  const int e = s >> 16, tt = s & 0xffff;
  int rem = counts[e] - tt * 128; if (rem > 128) rem = 128;
  const int ftb = blockIdx.x;   // 128 F-cols per block

  __shared__ __align__(16) bf16 As[3][4][128][8];      // 24 KB
  __shared__ __align__(16) bf16 Ws[3][2][4][128][8];   // 48 KB

  const int tid = threadIdx.x;
  const int lane = tid & 63;
  const int w = tid >> 6;
  const int wr = w >> 1, wc = w & 1;
  const int lh = lane >> 4, ll = lane & 15;

  // per-LANE staging sources
  const bf16* axg = xg + (size_t)blockIdx.y * XG_SLOT + w * 1024 + lane * 8;
  const int fh = w & 1;                 // which 64-col group of the 128
  const int kcp = (w >> 1) << 1;        // kc pair base: 0 or 2
  const size_t woff = ((size_t)(2 * ftb + fh) * 128 + kcp) * 512 + lane * 8;
  const bf16* w1w = w1b + (size_t)e * W_SLAB + woff;
  const bf16* w2w = w2b + (size_t)e * W_SLAB + woff;

  f32x4 acc1[4][4], acc2[4][4];
  const f32x4 fz = {0.f, 0.f, 0.f, 0.f};
#pragma unroll
  for (int mf = 0; mf < 4; ++mf)
#pragma unroll
    for (int nf = 0; nf < 4; ++nf) { acc1[mf][nf] = fz; acc2[mf][nf] = fz; }

  // 6 loads per wave per stage, each 1KB contiguous
#define STAGE1(B, KT)                                                    \
  {                                                                      \
    GLD16(axg + (size_t)(KT) * 4096,       &As[B][w][0][0]);             \
    GLD16(axg + (size_t)(KT) * 4096 + 512, &As[B][w][64][0]);            \
    GLD16(w1w + (size_t)(KT) * 2048,       &Ws[B][0][kcp][fh * 64][0]);  \
    GLD16(w1w + (size_t)(KT) * 2048 + 512, &Ws[B][0][kcp + 1][fh * 64][0]); \
    GLD16(w2w + (size_t)(KT) * 2048,       &Ws[B][1][kcp][fh * 64][0]);  \
    GLD16(w2w + (size_t)(KT) * 2048 + 512, &Ws[B][1][kcp + 1][fh * 64][0]); \
  }

  const int NT = DMODEL / 32;      // 32
  STAGE1(0, 0);
  STAGE1(1, 1);
  VMCNT(6);                         // tile 0 landed; tile 1 in flight
  __builtin_amdgcn_s_barrier();

  int ld = 0;
  for (int t = 0; t < NT; ++t) {
    int pf = ld + 2; if (pf >= 3) pf -= 3;
    if (t + 2 < NT) STAGE1(pf, t + 2);

    bf16x8 af[4], b1[4], b2[4];
#pragma unroll
    for (int mf = 0; mf < 4; ++mf)
      af[mf] = *(const bf16x8*)&As[ld][lh][wr * 64 + mf * 16 + ll][0];
#pragma unroll
    for (int nf = 0; nf < 4; ++nf) {
      b1[nf] = *(const bf16x8*)&Ws[ld][0][lh][wc * 64 + nf * 16 + ll][0];
      b2[nf] = *(const bf16x8*)&Ws[ld][1][lh][wc * 64 + nf * 16 + ll][0];
    }
    __builtin_amdgcn_s_setprio(1);
#pragma unroll
    for (int mf = 0; mf < 4; ++mf)
#pragma unroll
      for (int nf = 0; nf < 4; ++nf) {
        acc1[mf][nf] = __builtin_amdgcn_mfma_f32_16x16x32_bf16(af[mf], b1[nf], acc1[mf][nf], 0, 0, 0);
        acc2[mf][nf] = __builtin_amdgcn_mfma_f32_16x16x32_bf16(af[mf], b2[nf], acc2[mf][nf], 0, 0, 0);
      }
    __builtin_amdgcn_s_setprio(0);

    if (t + 2 < NT)      { VMCNT(6); __builtin_amdgcn_s_barrier(); }
    else if (t + 1 < NT) { VMCNT(0); __builtin_amdgcn_s_barrier(); }
    ld = (ld + 1 == 3) ? 0 : ld + 1;
  }
#undef STAGE1

  // epilogue: SiLU(a)*b -> blocked H [slot][ktf 64][kc 4][row 128][j 8]
  bf16* hs = hblk + (size_t)blockIdx.y * H_SLOT;
#pragma unroll
  for (int mf = 0; mf < 4; ++mf)
#pragma unroll
    for (int nf = 0; nf < 4; ++nf) {
      const int kth = ftb * 4 + wc * 2 + (nf >> 1);
      const int kch = (2 * nf + (ll >> 3)) & 3;
      bf16* hp = hs + ((size_t)kth * 4 + kch) * 1024 + (ll & 7);
#pragma unroll
      for (int r = 0; r < 4; ++r) {
        const int rl = wr * 64 + mf * 16 + lh * 4 + r;
        if (rl < rem) {
          const float a = acc1[mf][nf][r];
          const float b = acc2[mf][nf][r];
          const float h = (a / (1.f + expf(-a))) * b;
          hp[rl * 8] = (bf16)h;
        }
      }
    }
}

// ---------------- GEMM2: 128 tok x 128 D tile; Out += wgt*(H@W3); split-K x2 ----------------
__global__ __launch_bounds__(256) void moe_gemm2_blk(
    const bf16* __restrict__ hblk, const bf16* __restrict__ w3b,
    const int* __restrict__ tok_list, const float* __restrict__ wgt_list,
    const int* __restrict__ counts, const int* __restrict__ sched,
    float* __restrict__ out)
{
  const int s = sched[blockIdx.y];
  if (s < 0) return;
  const int e = s >> 16, tt = s & 0xffff;
  int rem = counts[e] - tt * 128; if (rem > 128) rem = 128;
  const int dtb = blockIdx.x;   // 128 D-cols per block
  const int kz = blockIdx.z;    // K half

  __shared__ __align__(16) bf16 As[4][4][128][8];   // 32 KB
  __shared__ __align__(16) bf16 Ws[4][4][128][8];   // 32 KB
  __shared__ int toks[128];
  __shared__ float wgts[128];

  const int tid = threadIdx.x;
  const int lane = tid & 63;
  const int w = tid >> 6;
  const int wr = w >> 1, wc = w & 1;
  const int lh = lane >> 4, ll = lane & 15;

  if (tid < 128) {
    int r = tid < rem ? tid : rem - 1;
    toks[tid] = tok_list[e * T_TOK + tt * 128 + r];
    wgts[tid] = wgt_list[e * T_TOK + tt * 128 + r];
  }
  __syncthreads();

  // per-LANE staging sources (both blocked, linear)
  const bf16* ah = hblk + (size_t)blockIdx.y * H_SLOT + (size_t)kz * 131072 + w * 1024 + lane * 8;
  const int fh = w & 1;
  const int kcp = (w >> 1) << 1;
  const bf16* w3w = w3b + (size_t)e * W_SLAB
      + ((size_t)(2 * dtb + fh) * 256 + (size_t)kz * 128 + kcp) * 512 + lane * 8;

  f32x4 acc[4][4];
  const f32x4 fz = {0.f, 0.f, 0.f, 0.f};
#pragma unroll
  for (int mf = 0; mf < 4; ++mf)
#pragma unroll
    for (int nf = 0; nf < 4; ++nf) acc[mf][nf] = fz;

  // 4 loads per wave per stage
#define STAGE2(B, KT)                                                    \
  {                                                                      \
    GLD16(ah  + (size_t)(KT) * 4096,       &As[B][w][0][0]);             \
    GLD16(ah  + (size_t)(KT) * 4096 + 512, &As[B][w][64][0]);            \
    GLD16(w3w + (size_t)(KT) * 2048,       &Ws[B][kcp][fh * 64][0]);     \
    GLD16(w3w + (size_t)(KT) * 2048 + 512, &Ws[B][kcp + 1][fh * 64][0]); \
  }

  const int NT = (FDIM / 2) / 32;   // 32
  STAGE2(0, 0);
  STAGE2(1, 1);
  STAGE2(2, 2);
  VMCNT(8);                          // tile 0 landed; tiles 1,2 in flight
  __builtin_amdgcn_s_barrier();

  int ld = 0;
  for (int t = 0; t < NT; ++t) {
    int pf = ld + 3; if (pf >= 4) pf -= 4;
    if (t + 3 < NT) STAGE2(pf, t + 3);

    bf16x8 af[4], bv[4];
#pragma unroll
    for (int mf = 0; mf < 4; ++mf)
      af[mf] = *(const bf16x8*)&As[ld][lh][wr * 64 + mf * 16 + ll][0];
#pragma unroll
    for (int nf = 0; nf < 4; ++nf)
      bv[nf] = *(const bf16x8*)&Ws[ld][lh][wc * 64 + nf * 16 + ll][0];
    __builtin_amdgcn_s_setprio(1);
#pragma unroll
    for (int mf = 0; mf < 4; ++mf)
#pragma unroll
      for (int nf = 0; nf < 4; ++nf)
        acc[mf][nf] = __builtin_amdgcn_mfma_f32_16x16x32_bf16(af[mf], bv[nf], acc[mf][nf], 0, 0, 0);
    __builtin_amdgcn_s_setprio(0);

    if (t + 3 < NT)      { VMCNT(8); __builtin_amdgcn_s_barrier(); }
    else if (t + 2 < NT) { VMCNT(4); __builtin_amdgcn_s_barrier(); }
    else if (t + 1 < NT) { VMCNT(0); __builtin_amdgcn_s_barrier(); }
    ld = (ld + 1 == 4) ? 0 : ld + 1;
  }
#undef STAGE2

#pragma unroll
  for (int mf = 0; mf < 4; ++mf)
#pragma unroll
    for (int nf = 0; nf < 4; ++nf)
#pragma unroll
      for (int r = 0; r < 4; ++r) {
        const int rl = wr * 64 + mf * 16 + lh * 4 + r;
        if (rl < rem) {
          const int col = dtb * 128 + wc * 64 + nf * 16 + ll;
          atomicAdd(&out[(size_t)toks[rl] * DMODEL + col], acc[mf][nf][r] * wgts[rl]);
        }
      }
}

// ================= FALLBACK (round-1 style) — used only if ws too small =================
__global__ __launch_bounds__(256, 2) void moe_gemm1(
    const bf16* __restrict__ xb,
    const float* __restrict__ w1, const float* __restrict__ w2,
    const int* __restrict__ tok_list, const int* __restrict__ counts,
    const int* __restrict__ base, bf16* __restrict__ H)
{
  const int e = blockIdx.z;
  const int tt = blockIdx.y;
  const int ft = blockIdx.x;
  const int cnt = counts[e];
  if (tt * 128 >= cnt) return;
  int rem = cnt - tt * 128; if (rem > 128) rem = 128;

  __shared__ __align__(16) bf16 As[4][128][8];
  __shared__ __align__(16) bf16 Ws[2][4][64][8];
  __shared__ int toks[128];

  const int tid = threadIdx.x;
  const int lane = tid & 63;
  const int w = tid >> 6;
  const int wr = w >> 1, wc = w & 1;
  const int lh = lane >> 4, ll = lane & 15;

  if (tid < 128) {
    int r = tid < rem ? tid : rem - 1;
    toks[tid] = tok_list[e * T_TOK + tt * 128 + r];
  }
  __syncthreads();

  f32x4 acc1[4][2], acc2[4][2];
  const f32x4 fz = {0.f, 0.f, 0.f, 0.f};
#pragma unroll
  for (int mf = 0; mf < 4; ++mf)
#pragma unroll
    for (int nf = 0; nf < 2; ++nf) { acc1[mf][nf] = fz; acc2[mf][nf] = fz; }

  const float* w1e = w1 + (size_t)e * DMODEL * FDIM + ft * 64;
  const float* w2e = w2 + (size_t)e * DMODEL * FDIM + ft * 64;
  const int sf = tid & 63;
  const int skc = tid >> 6;

  for (int k0 = 0; k0 < DMODEL; k0 += 32) {
    __syncthreads();
#pragma unroll
    for (int i = 0; i < 2; ++i) {
      const int c = w + i * 4;
      const int kc = c >> 1;
      const int rh = c & 1;
      const int row = rh * 64 + lane;
      GLD16(xb + (size_t)toks[row] * DMODEL + (k0 + kc * 8), &As[kc][rh * 64][0]);
    }
    {
      const size_t rowoff = (size_t)(k0 + skc * 8) * FDIM + sf;
      const float* s1 = w1e + rowoff;
      const float* s2 = w2e + rowoff;
      bf16x8 v1, v2;
#pragma unroll
      for (int j = 0; j < 8; ++j) {
        v1[j] = (bf16)s1[(size_t)j * FDIM];
        v2[j] = (bf16)s2[(size_t)j * FDIM];
      }
      *(bf16x8*)&Ws[0][skc][sf][0] = v1;
      *(bf16x8*)&Ws[1][skc][sf][0] = v2;
    }
    __syncthreads();
    bf16x8 af[4];
#pragma unroll
    for (int mf = 0; mf < 4; ++mf)
      af[mf] = *(const bf16x8*)&As[lh][wr * 64 + mf * 16 + ll][0];
    bf16x8 b1[2], b2[2];
#pragma unroll
    for (int nf = 0; nf < 2; ++nf) {
      b1[nf] = *(const bf16x8*)&Ws[0][lh][wc * 32 + nf * 16 + ll][0];
      b2[nf] = *(const bf16x8*)&Ws[1][lh][wc * 32 + nf * 16 + ll][0];
    }
#pragma unroll
    for (int mf = 0; mf < 4; ++mf)
#pragma unroll
      for (int nf = 0; nf < 2; ++nf) {
        acc1[mf][nf] = __builtin_amdgcn_mfma_f32_16x16x32_bf16(af[mf], b1[nf], acc1[mf][nf], 0, 0, 0);
        acc2[mf][nf] = __builtin_amdgcn_mfma_f32_16x16x32_bf16(af[mf], b2[nf], acc2[mf][nf], 0, 0, 0);
      }
  }

  const int hbase = base[e] + tt * 128;
#pragma unroll
  for (int mf = 0; mf < 4; ++mf)
#pragma unroll
    for (int nf = 0; nf < 2; ++nf)
#pragma unroll
      for (int r = 0; r < 4; ++r) {
        const int rl = wr * 64 + mf * 16 + lh * 4 + r;
        if (rl < rem) {
          const int fg = ft * 64 + wc * 32 + nf * 16 + ll;
          const float a = acc1[mf][nf][r];
          const float b = acc2[mf][nf][r];
          const float h = (a / (1.f + expf(-a))) * b;
          H[(size_t)(hbase + rl) * FDIM + fg] = (bf16)h;
        }
      }
}

__global__ __launch_bounds__(256, 2) void moe_gemm2(
    const bf16* __restrict__ H, const float* __restrict__ w3,
    const int* __restrict__ tok_list, const float* __restrict__ wgt_list,
    const int* __restrict__ counts, const int* __restrict__ base,
    float* __restrict__ out)
{
  const int e = blockIdx.z;
  const int tt = blockIdx.y;
  const int dt = blockIdx.x;
  const int cnt = counts[e];
  if (tt * 128 >= cnt) return;
  int rem = cnt - tt * 128; if (rem > 128) rem = 128;

  __shared__ __align__(16) bf16 As[4][128][8];
  __shared__ __align__(16) bf16 Ws[4][64][8];
  __shared__ int toks[128];
  __shared__ float wgts[128];

  const int tid = threadIdx.x;
  const int lane = tid & 63;
  const int w = tid >> 6;
  const int wr = w >> 1, wc = w & 1;
  const int lh = lane >> 4, ll = lane & 15;

  if (tid < 128) {
    int r = tid < rem ? tid : rem - 1;
    toks[tid] = tok_list[e * T_TOK + tt * 128 + r];
    wgts[tid] = wgt_list[e * T_TOK + tt * 128 + r];
  }
  __syncthreads();

  f32x4 acc[4][2];
  const f32x4 fz = {0.f, 0.f, 0.f, 0.f};
#pragma unroll
  for (int mf = 0; mf < 4; ++mf)
#pragma unroll
    for (int nf = 0; nf < 2; ++nf) acc[mf][nf] = fz;

  const int hbase = base[e] + tt * 128;
  const float* w3e = w3 + (size_t)e * FDIM * DMODEL + dt * 64;
  const int sf = tid & 63;
  const int skc = tid >> 6;

  for (int k0 = 0; k0 < FDIM; k0 += 32) {
    __syncthreads();
#pragma unroll
    for (int i = 0; i < 2; ++i) {
      const int c = w + i * 4;
      const int kc = c >> 1;
      const int rh = c & 1;
      int row = rh * 64 + lane;
      if (row >= rem) row = rem - 1;
      GLD16(H + (size_t)(hbase + row) * FDIM + (k0 + kc * 8), &As[kc][rh * 64][0]);
    }
    {
      const size_t rowoff = (size_t)(k0 + skc * 8) * DMODEL + sf;
      const float* s3 = w3e + rowoff;
      bf16x8 v;
#pragma unroll
      for (int j = 0; j < 8; ++j) v[j] = (bf16)s3[(size_t)j * DMODEL];
      *(bf16x8*)&Ws[skc][sf][0] = v;
    }
    __syncthreads();
    bf16x8 af[4];
#pragma unroll
    for (int mf = 0; mf < 4; ++mf)
      af[mf] = *(const bf16x8*)&As[lh][wr * 64 + mf * 16 + ll][0];
    bf16x8 bv[2];
#pragma unroll
    for (int nf = 0; nf < 2; ++nf)
      bv[nf] = *(const bf16x8*)&Ws[lh][wc * 32 + nf * 16 + ll][0];
#pragma unroll
    for (int mf = 0; mf < 4; ++mf)
#pragma unroll
      for (int nf = 0; nf < 2; ++nf)
        acc[mf][nf] = __builtin_amdgcn_mfma_f32_16x16x32_bf16(af[mf], bv[nf], acc[mf][nf], 0, 0, 0);
  }

#pragma unroll
  for (int mf = 0; mf < 4; ++mf)
#pragma unroll
    for (int nf = 0; nf < 2; ++nf)
#pragma unroll
      for (int r = 0; r < 4; ++r) {
        const int rl = wr * 64 + mf * 16 + lh * 4 + r;
        if (rl < rem) {
          const int col = dt * 64 + wc * 32 + nf * 16 + ll;
          atomicAdd(&out[(size_t)toks[rl] * DMODEL + col], acc[mf][nf][r] * wgts[rl]);
        }
      }
}

extern "C" void kernel_launch(void* const* d_in, const int* in_sizes, int n_in,
                              void* d_out, int out_size, void* d_ws, size_t ws_size,
                              hipStream_t stream)
{
  const float* x  = (const float*)d_in[0];
  const float* rw = (const float*)d_in[1];
  const float* w1 = (const float*)d_in[2];
  const float* w2 = (const float*)d_in[3];
  const float* w3 = (const float*)d_in[4];
  float* out = (float*)d_out;
  char* ws = (char*)d_ws;

  // ---- blocked-path layout ----
  size_t off = 0;
  auto take = [&](size_t bytes) -> char* {
    char* p = ws + off;
    off = (off + bytes + 255) & ~(size_t)255;
    return p;
  };
  int* tok_list   = (int*)take((size_t)NEXP * T_TOK * sizeof(int));
  float* wgt_list = (float*)take((size_t)NEXP * T_TOK * sizeof(float));
  int* counts     = (int*)take(64);
  int* base       = (int*)take(64);
  int* sched      = (int*)take(MAXS * sizeof(int));
  bf16* xg        = (bf16*)take((size_t)MAXS * XG_SLOT * sizeof(bf16));   // 10.5 MiB
  bf16* hblk      = (bf16*)take((size_t)MAXS * H_SLOT * sizeof(bf16));    // 21 MiB
  bf16* w1b       = (bf16*)take((size_t)NEXP * W_SLAB * sizeof(bf16));    // 32 MiB
  bf16* w2b       = (bf16*)take((size_t)NEXP * W_SLAB * sizeof(bf16));    // 32 MiB
  bf16* w3b       = (bf16*)take((size_t)NEXP * W_SLAB * sizeof(bf16));    // 32 MiB
  const bool fast = (ws_size >= off);

  hipMemsetAsync(d_out, 0, (size_t)out_size * sizeof(float), stream);
  hipMemsetAsync(counts, 0, NEXP * sizeof(int), stream);

  if (fast) {
    moe_router<<<dim3(T_TOK), dim3(64), 0, stream>>>(x, rw, nullptr, counts, tok_list, wgt_list);
    moe_prefix<<<dim3(1), dim3(64), 0, stream>>>(counts, base, sched);
    transpose_blk12<<<dim3(FDIM / 64, DMODEL / 64, 2 * NEXP), dim3(256), 0, stream>>>(w1, w2, w1b, w2b);
    transpose_blk3<<<dim3(DMODEL / 64, FDIM / 64, NEXP), dim3(256), 0, stream>>>(w3, w3b);
    moe_gather<<<dim3(MAXS, 32), dim3(256), 0, stream>>>(x, tok_list, counts, sched, xg);
    moe_gemm1_blk<<<dim3(FDIM / 128, MAXS), dim3(256), 0, stream>>>(
        xg, w1b, w2b, counts, sched, hblk);
    moe_gemm2_blk<<<dim3(DMODEL / 128, MAXS, 2), dim3(256), 0, stream>>>(
        hblk, w3b, tok_list, wgt_list, counts, sched, out);
  } else {
    // fallback layout: xb + flat H only
    size_t foff = 0;
    auto ftake = [&](size_t bytes) -> char* {
      char* p = ws + foff;
      foff = (foff + bytes + 255) & ~(size_t)255;
      return p;
    };
    int* ftok   = (int*)ftake((size_t)NEXP * T_TOK * sizeof(int));
    float* fwgt = (float*)ftake((size_t)NEXP * T_TOK * sizeof(float));
    int* fcnt   = (int*)ftake(64);
    int* fbase  = (int*)ftake(64);
    int* fsched = (int*)ftake(MAXS * sizeof(int));
    bf16* xb    = (bf16*)ftake((size_t)T_TOK * DMODEL * sizeof(bf16));
    bf16* H     = (bf16*)ftake((size_t)2 * T_TOK * FDIM * sizeof(bf16));
    hipMemsetAsync(fcnt, 0, NEXP * sizeof(int), stream);
    moe_router<<<dim3(T_TOK), dim3(64), 0, stream>>>(x, rw, xb, fcnt, ftok, fwgt);
    moe_prefix<<<dim3(1), dim3(64), 0, stream>>>(fcnt, fbase, fsched);
    moe_gemm1<<<dim3(FDIM / 64, T_TOK / 128, NEXP), dim3(256), 0, stream>>>(
        xb, w1, w2, ftok, fcnt, fbase, H);
    moe_gemm2<<<dim3(DMODEL / 64, T_TOK / 128, NEXP), dim3(256), 0, stream>>>(
        H, w3, ftok, fwgt, fcnt, fbase, out);
  }
}

// Round 7
// 245.786 us; speedup vs baseline: 1.3268x; 1.3268x over previous
//
#include <hip/hip_runtime.h>
#include <hip/hip_bf16.h>
#include <stdint.h>

#define T_TOK 2048
#define DMODEL 1024
#define FDIM 2048
#define NEXP 8
#define MAXS 40   // sum ceil(c_e/128) <= 4096/128 + 8 = 40

typedef __bf16 bf16;
typedef __attribute__((ext_vector_type(8))) __bf16 bf16x8;
typedef __attribute__((ext_vector_type(4))) float f32x4;

#define GLOBAL_AS __attribute__((address_space(1)))
#define LDS_AS __attribute__((address_space(3)))
#define VMCNT(n) asm volatile("s_waitcnt vmcnt(" #n ")" ::: "memory")
#define GLD16(src, dst) __builtin_amdgcn_global_load_lds((const GLOBAL_AS void*)(src), (LDS_AS void*)(dst), 16, 0, 0)

// slab sizes in bf16 elements
#define XG_SLOT   131072u   // 32 kt * 4 kc * 128 rows * 8
#define H_SLOT    262144u   // 64 kt * 4 kc * 128 rows * 8
#define W_SLAB    2097152u  // per-expert blocked weight slab (D*F)

// ---------------- Router: fp32 logits, top-2, renormalized weights ----------------
__global__ __launch_bounds__(64) void moe_router(
    const float* __restrict__ x, const float* __restrict__ rw,
    bf16* __restrict__ xb, int* __restrict__ counts,
    int* __restrict__ tok_list, float* __restrict__ wgt_list)
{
  const int t = blockIdx.x;
  const int lane = threadIdx.x;
  const float* xr = x + (size_t)t * DMODEL;
  float acc[NEXP];
#pragma unroll
  for (int e = 0; e < NEXP; ++e) acc[e] = 0.f;
  for (int d = lane; d < DMODEL; d += 64) {
    float xv = xr[d];
    if (xb) xb[(size_t)t * DMODEL + d] = (bf16)xv;   // only for fallback path
    const float* r = rw + (size_t)d * NEXP;
#pragma unroll
    for (int e = 0; e < NEXP; ++e) acc[e] += xv * r[e];
  }
#pragma unroll
  for (int e = 0; e < NEXP; ++e) {
#pragma unroll
    for (int off = 32; off >= 1; off >>= 1)
      acc[e] += __shfl_xor(acc[e], off, 64);
  }
  if (lane == 0) {
    int i0 = 0; float m0 = acc[0];
#pragma unroll
    for (int e = 1; e < NEXP; ++e) { if (acc[e] > m0) { m0 = acc[e]; i0 = e; } }
    int i1 = -1; float m1 = -3.402823466e38f;
#pragma unroll
    for (int e = 0; e < NEXP; ++e) { if (e != i0 && acc[e] > m1) { m1 = acc[e]; i1 = e; } }
    float r = expf(m1 - m0);               // p1/p0; softmax denominator cancels
    float w0 = 1.f / (1.f + r);
    float w1v = r / (1.f + r);
    int p0 = atomicAdd(&counts[i0], 1);
    tok_list[i0 * T_TOK + p0] = t;
    wgt_list[i0 * T_TOK + p0] = w0;
    int p1 = atomicAdd(&counts[i1], 1);
    tok_list[i1 * T_TOK + p1] = t;
    wgt_list[i1 * T_TOK + p1] = w1v;
  }
}

// ---------------- Prefix + dense tile schedule ----------------
__global__ void moe_prefix(const int* __restrict__ counts, int* __restrict__ base,
                           int* __restrict__ sched)
{
  if (threadIdx.x == 0) {
    int s = 0, i = 0;
    for (int e = 0; e < NEXP; ++e) {
      base[e] = s; s += counts[e];
      const int nt = (counts[e] + 127) / 128;
      for (int tt = 0; tt < nt; ++tt) sched[i++] = (e << 16) | tt;
    }
    for (; i < MAXS; ++i) sched[i] = -1;
  }
}

// ---------------- Gather routed token rows into blocked Xg [slot][kt][kc][128][8] ----------------
__global__ __launch_bounds__(256) void moe_gather(
    const float* __restrict__ x, const int* __restrict__ tok_list,
    const int* __restrict__ counts, const int* __restrict__ sched,
    bf16* __restrict__ xg)
{
  const int s = sched[blockIdx.x];
  if (s < 0) return;
  const int e = s >> 16, tt = s & 0xffff;
  int rem = counts[e] - tt * 128; if (rem > 128) rem = 128;
  const int w = threadIdx.x >> 6, lane = threadIdx.x & 63;
  const int r = blockIdx.y * 4 + w;           // 0..127
  const int rc = r < rem ? r : rem - 1;
  const int tok = tok_list[e * T_TOK + tt * 128 + rc];
  const float* xr = x + (size_t)tok * DMODEL + lane * 16;   // 64B/lane, coalesced
  f32x4 v0 = *(const f32x4*)(xr);
  f32x4 v1 = *(const f32x4*)(xr + 4);
  f32x4 v2 = *(const f32x4*)(xr + 8);
  f32x4 v3 = *(const f32x4*)(xr + 12);
  bf16x8 a, b;
#pragma unroll
  for (int j = 0; j < 4; ++j) { a[j] = (bf16)v0[j]; a[4 + j] = (bf16)v1[j]; }
#pragma unroll
  for (int j = 0; j < 4; ++j) { b[j] = (bf16)v2[j]; b[4 + j] = (bf16)v3[j]; }
  // lane covers d = lane*16 .. +15 -> chunk indices (d/8) = 2*lane, 2*lane+1
  bf16* dst = xg + (size_t)blockIdx.x * XG_SLOT + (size_t)(lane * 2) * 1024 + r * 8;
  *(bf16x8*)dst = a;
  *(bf16x8*)(dst + 1024) = b;
}

// ---------------- Transpose + cvt into blocked weight layouts ----------------
// w1/w2 (D,F) -> [e][ft F/64][ktd D/32][kc 4][fi 64][j 8]
__global__ __launch_bounds__(256) void transpose_blk12(
    const float* __restrict__ w1, const float* __restrict__ w2,
    bf16* __restrict__ w1b, bf16* __restrict__ w2b)
{
  const int C = FDIM;
  __shared__ float tile[64][65];
  const int z = blockIdx.z;
  const int e = z & 7;
  const float* inp = (z < 8 ? w1 : w2) + (size_t)e * DMODEL * FDIM;
  bf16* outp = (z < 8 ? w1b : w2b) + (size_t)e * W_SLAB;
  const int rb = blockIdx.y * 64;   // over D
  const int cb = blockIdx.x * 64;   // over F
  const int tid = threadIdx.x;
  const int r = tid >> 2, c0 = (tid & 3) * 16;
  const float* src = inp + (size_t)(rb + r) * C + (cb + c0);
#pragma unroll
  for (int j = 0; j < 16; j += 4) {
    f32x4 v = *(const f32x4*)(src + j);
    tile[r][c0 + j + 0] = v[0];
    tile[r][c0 + j + 1] = v[1];
    tile[r][c0 + j + 2] = v[2];
    tile[r][c0 + j + 3] = v[3];
  }
  __syncthreads();
  // this thread outputs f-row (cb+r), d-range rb+c0 .. +15
  bf16x8 a, b;
#pragma unroll
  for (int j = 0; j < 8; ++j) a[j] = (bf16)tile[c0 + j][r];
#pragma unroll
  for (int j = 0; j < 8; ++j) b[j] = (bf16)tile[c0 + 8 + j][r];
  const int ft = blockIdx.x;                 // cb/64
  const int ktd = blockIdx.y * 2 + c0 / 32;  // (rb+c0)/32
  const int kc = (c0 & 31) / 8;              // 0 or 2
  bf16* dst = outp + ((size_t)ft * 128 + ktd * 4 + kc) * 512 + r * 8;
  *(bf16x8*)dst = a;
  *(bf16x8*)(dst + 512) = b;                 // kc+1
}

// w3 (F,D) -> [e][dt D/64][ktf F/32][kc 4][di 64][j 8]
__global__ __launch_bounds__(256) void transpose_blk3(
    const float* __restrict__ w3, bf16* __restrict__ w3b)
{
  const int C = DMODEL;
  __shared__ float tile[64][65];
  const int e = blockIdx.z;
  const float* inp = w3 + (size_t)e * FDIM * DMODEL;
  bf16* outp = w3b + (size_t)e * W_SLAB;
  const int rb = blockIdx.y * 64;   // over F
  const int cb = blockIdx.x * 64;   // over D
  const int tid = threadIdx.x;
  const int r = tid >> 2, c0 = (tid & 3) * 16;
  const float* src = inp + (size_t)(rb + r) * C + (cb + c0);
#pragma unroll
  for (int j = 0; j < 16; j += 4) {
    f32x4 v = *(const f32x4*)(src + j);
    tile[r][c0 + j + 0] = v[0];
    tile[r][c0 + j + 1] = v[1];
    tile[r][c0 + j + 2] = v[2];
    tile[r][c0 + j + 3] = v[3];
  }
  __syncthreads();
  // outputs d-row (cb+r), f-range rb+c0 .. +15
  bf16x8 a, b;
#pragma unroll
  for (int j = 0; j < 8; ++j) a[j] = (bf16)tile[c0 + j][r];
#pragma unroll
  for (int j = 0; j < 8; ++j) b[j] = (bf16)tile[c0 + 8 + j][r];
  const int dt = blockIdx.x;
  const int ktf = blockIdx.y * 2 + c0 / 32;
  const int kc = (c0 & 31) / 8;
  bf16* dst = outp + ((size_t)dt * 256 + ktf * 4 + kc) * 512 + r * 8;
  *(bf16x8*)dst = a;
  *(bf16x8*)(dst + 512) = b;
}

// ---------------- GEMM1: 128 tok x 64 F tile (round-5 proven); H = silu(Xg@W1)*(Xg@W2) ----------------
__global__ __launch_bounds__(256) void moe_gemm1_blk(
    const bf16* __restrict__ xg,
    const bf16* __restrict__ w1b, const bf16* __restrict__ w2b,
    const int* __restrict__ counts, const int* __restrict__ sched,
    bf16* __restrict__ hblk)
{
  const int s = sched[blockIdx.y];
  if (s < 0) return;
  const int e = s >> 16, tt = s & 0xffff;
  int rem = counts[e] - tt * 128; if (rem > 128) rem = 128;
  const int ft = blockIdx.x;

  __shared__ __align__(16) bf16 As[3][4][128][8];      // 24 KB
  __shared__ __align__(16) bf16 Ws[3][2][4][64][8];    // 24 KB

  const int tid = threadIdx.x;
  const int lane = tid & 63;
  const int w = tid >> 6;
  const int wr = w >> 1, wc = w & 1;
  const int lh = lane >> 4, ll = lane & 15;

  // per-LANE staging sources (blocked layouts): lane l fetches 16B chunk l
  const bf16* axg = xg + (size_t)blockIdx.y * XG_SLOT + w * 1024 + lane * 8;
  const bf16* w1e = w1b + (size_t)e * W_SLAB + ((size_t)ft * 128 + w) * 512 + lane * 8;
  const bf16* w2e = w2b + (size_t)e * W_SLAB + ((size_t)ft * 128 + w) * 512 + lane * 8;

  f32x4 acc1[4][2], acc2[4][2];
  const f32x4 fz = {0.f, 0.f, 0.f, 0.f};
#pragma unroll
  for (int mf = 0; mf < 4; ++mf)
#pragma unroll
    for (int nf = 0; nf < 2; ++nf) { acc1[mf][nf] = fz; acc2[mf][nf] = fz; }

  // 4 loads per wave per stage, each 1KB contiguous
#define STAGE1(B, KT)                                              \
  {                                                                \
    GLD16(axg + (size_t)(KT) * 4096,       &As[B][w][0][0]);       \
    GLD16(axg + (size_t)(KT) * 4096 + 512, &As[B][w][64][0]);      \
    GLD16(w1e + (size_t)(KT) * 2048,       &Ws[B][0][w][0][0]);    \
    GLD16(w2e + (size_t)(KT) * 2048,       &Ws[B][1][w][0][0]);    \
  }

  const int NT = DMODEL / 32;      // 32
  STAGE1(0, 0);
  STAGE1(1, 1);
  VMCNT(4);
  __builtin_amdgcn_s_barrier();

  int ld = 0;
  for (int t = 0; t < NT; ++t) {
    int pf = ld + 2; if (pf >= 3) pf -= 3;
    if (t + 2 < NT) STAGE1(pf, t + 2);

    bf16x8 af[4], b1[2], b2[2];
#pragma unroll
    for (int mf = 0; mf < 4; ++mf)
      af[mf] = *(const bf16x8*)&As[ld][lh][wr * 64 + mf * 16 + ll][0];
#pragma unroll
    for (int nf = 0; nf < 2; ++nf) {
      b1[nf] = *(const bf16x8*)&Ws[ld][0][lh][wc * 32 + nf * 16 + ll][0];
      b2[nf] = *(const bf16x8*)&Ws[ld][1][lh][wc * 32 + nf * 16 + ll][0];
    }
    __builtin_amdgcn_s_setprio(1);
#pragma unroll
    for (int mf = 0; mf < 4; ++mf)
#pragma unroll
      for (int nf = 0; nf < 2; ++nf) {
        acc1[mf][nf] = __builtin_amdgcn_mfma_f32_16x16x32_bf16(af[mf], b1[nf], acc1[mf][nf], 0, 0, 0);
        acc2[mf][nf] = __builtin_amdgcn_mfma_f32_16x16x32_bf16(af[mf], b2[nf], acc2[mf][nf], 0, 0, 0);
      }
    __builtin_amdgcn_s_setprio(0);

    if (t + 2 < NT)      { VMCNT(4); __builtin_amdgcn_s_barrier(); }
    else if (t + 1 < NT) { VMCNT(0); __builtin_amdgcn_s_barrier(); }
    ld = (ld + 1 == 3) ? 0 : ld + 1;
  }
#undef STAGE1

  // epilogue: SiLU(a)*b -> blocked H [slot][ktf 64][kc 4][row 128][j 8]
  bf16* hs = hblk + (size_t)blockIdx.y * H_SLOT;
  const int kth = ft * 2 + wc;
#pragma unroll
  for (int mf = 0; mf < 4; ++mf)
#pragma unroll
    for (int nf = 0; nf < 2; ++nf) {
      const int kch = nf * 2 + (ll >> 3);
      bf16* hp = hs + ((size_t)kth * 4 + kch) * 1024 + (ll & 7);
#pragma unroll
      for (int r = 0; r < 4; ++r) {
        const int rl = wr * 64 + mf * 16 + lh * 4 + r;
        if (rl < rem) {
          const float a = acc1[mf][nf][r];
          const float b = acc2[mf][nf][r];
          const float h = (a / (1.f + expf(-a))) * b;
          hp[rl * 8] = (bf16)h;
        }
      }
    }
}

// ---------------- GEMM2: 128 tok x 128 D tile, acc[4][4], ring-3; split-K x2 ----------------
__global__ __launch_bounds__(256) void moe_gemm2_blk(
    const bf16* __restrict__ hblk, const bf16* __restrict__ w3b,
    const int* __restrict__ tok_list, const float* __restrict__ wgt_list,
    const int* __restrict__ counts, const int* __restrict__ sched,
    float* __restrict__ out)
{
  const int s = sched[blockIdx.y];
  if (s < 0) return;
  const int e = s >> 16, tt = s & 0xffff;
  int rem = counts[e] - tt * 128; if (rem > 128) rem = 128;
  const int dtb = blockIdx.x;   // 128 D-cols per block
  const int kz = blockIdx.z;    // K half

  __shared__ __align__(16) bf16 As[3][4][128][8];   // 24 KB
  __shared__ __align__(16) bf16 Ws[3][4][128][8];   // 24 KB
  __shared__ int toks[128];
  __shared__ float wgts[128];

  const int tid = threadIdx.x;
  const int lane = tid & 63;
  const int w = tid >> 6;
  const int wr = w >> 1, wc = w & 1;
  const int lh = lane >> 4, ll = lane & 15;

  if (tid < 128) {
    int r = tid < rem ? tid : rem - 1;
    toks[tid] = tok_list[e * T_TOK + tt * 128 + r];
    wgts[tid] = wgt_list[e * T_TOK + tt * 128 + r];
  }
  __syncthreads();

  // per-LANE staging sources (both blocked, linear)
  const bf16* ah = hblk + (size_t)blockIdx.y * H_SLOT + (size_t)kz * 131072 + w * 1024 + lane * 8;
  const int fh = w & 1;                 // which 64-col group of the 128
  const int kcp = (w >> 1) << 1;        // kc pair base: 0 or 2
  const bf16* w3w = w3b + (size_t)e * W_SLAB
      + ((size_t)(2 * dtb + fh) * 256 + (size_t)kz * 128 + kcp) * 512 + lane * 8;

  f32x4 acc[4][4];
  const f32x4 fz = {0.f, 0.f, 0.f, 0.f};
#pragma unroll
  for (int mf = 0; mf < 4; ++mf)
#pragma unroll
    for (int nf = 0; nf < 4; ++nf) acc[mf][nf] = fz;

  // 4 loads per wave per stage, each 1KB contiguous
#define STAGE2(B, KT)                                                    \
  {                                                                      \
    GLD16(ah  + (size_t)(KT) * 4096,       &As[B][w][0][0]);             \
    GLD16(ah  + (size_t)(KT) * 4096 + 512, &As[B][w][64][0]);            \
    GLD16(w3w + (size_t)(KT) * 2048,       &Ws[B][kcp][fh * 64][0]);     \
    GLD16(w3w + (size_t)(KT) * 2048 + 512, &Ws[B][kcp + 1][fh * 64][0]); \
  }

  const int NT = (FDIM / 2) / 32;   // 32
  STAGE2(0, 0);
  STAGE2(1, 1);
  VMCNT(4);
  __builtin_amdgcn_s_barrier();

  int ld = 0;
  for (int t = 0; t < NT; ++t) {
    int pf = ld + 2; if (pf >= 3) pf -= 3;
    if (t + 2 < NT) STAGE2(pf, t + 2);

    bf16x8 af[4], bv[4];
#pragma unroll
    for (int mf = 0; mf < 4; ++mf)
      af[mf] = *(const bf16x8*)&As[ld][lh][wr * 64 + mf * 16 + ll][0];
#pragma unroll
    for (int nf = 0; nf < 4; ++nf)
      bv[nf] = *(const bf16x8*)&Ws[ld][lh][wc * 64 + nf * 16 + ll][0];
    __builtin_amdgcn_s_setprio(1);
#pragma unroll
    for (int mf = 0; mf < 4; ++mf)
#pragma unroll
      for (int nf = 0; nf < 4; ++nf)
        acc[mf][nf] = __builtin_amdgcn_mfma_f32_16x16x32_bf16(af[mf], bv[nf], acc[mf][nf], 0, 0, 0);
    __builtin_amdgcn_s_setprio(0);

    if (t + 2 < NT)      { VMCNT(4); __builtin_amdgcn_s_barrier(); }
    else if (t + 1 < NT) { VMCNT(0); __builtin_amdgcn_s_barrier(); }
    ld = (ld + 1 == 3) ? 0 : ld + 1;
  }
#undef STAGE2

#pragma unroll
  for (int mf = 0; mf < 4; ++mf)
#pragma unroll
    for (int nf = 0; nf < 4; ++nf)
#pragma unroll
      for (int r = 0; r < 4; ++r) {
        const int rl = wr * 64 + mf * 16 + lh * 4 + r;
        if (rl < rem) {
          const int col = dtb * 128 + wc * 64 + nf * 16 + ll;
          atomicAdd(&out[(size_t)toks[rl] * DMODEL + col], acc[mf][nf][r] * wgts[rl]);
        }
      }
}

// ================= FALLBACK (round-1 style) — used only if ws too small =================
__global__ __launch_bounds__(256, 2) void moe_gemm1(
    const bf16* __restrict__ xb,
    const float* __restrict__ w1, const float* __restrict__ w2,
    const int* __restrict__ tok_list, const int* __restrict__ counts,
    const int* __restrict__ base, bf16* __restrict__ H)
{
  const int e = blockIdx.z;
  const int tt = blockIdx.y;
  const int ft = blockIdx.x;
  const int cnt = counts[e];
  if (tt * 128 >= cnt) return;
  int rem = cnt - tt * 128; if (rem > 128) rem = 128;

  __shared__ __align__(16) bf16 As[4][128][8];
  __shared__ __align__(16) bf16 Ws[2][4][64][8];
  __shared__ int toks[128];

  const int tid = threadIdx.x;
  const int lane = tid & 63;
  const int w = tid >> 6;
  const int wr = w >> 1, wc = w & 1;
  const int lh = lane >> 4, ll = lane & 15;

  if (tid < 128) {
    int r = tid < rem ? tid : rem - 1;
    toks[tid] = tok_list[e * T_TOK + tt * 128 + r];
  }
  __syncthreads();

  f32x4 acc1[4][2], acc2[4][2];
  const f32x4 fz = {0.f, 0.f, 0.f, 0.f};
#pragma unroll
  for (int mf = 0; mf < 4; ++mf)
#pragma unroll
    for (int nf = 0; nf < 2; ++nf) { acc1[mf][nf] = fz; acc2[mf][nf] = fz; }

  const float* w1e = w1 + (size_t)e * DMODEL * FDIM + ft * 64;
  const float* w2e = w2 + (size_t)e * DMODEL * FDIM + ft * 64;
  const int sf = tid & 63;
  const int skc = tid >> 6;

  for (int k0 = 0; k0 < DMODEL; k0 += 32) {
    __syncthreads();
#pragma unroll
    for (int i = 0; i < 2; ++i) {
      const int c = w + i * 4;
      const int kc = c >> 1;
      const int rh = c & 1;
      const int row = rh * 64 + lane;
      GLD16(xb + (size_t)toks[row] * DMODEL + (k0 + kc * 8), &As[kc][rh * 64][0]);
    }
    {
      const size_t rowoff = (size_t)(k0 + skc * 8) * FDIM + sf;
      const float* s1 = w1e + rowoff;
      const float* s2 = w2e + rowoff;
      bf16x8 v1, v2;
#pragma unroll
      for (int j = 0; j < 8; ++j) {
        v1[j] = (bf16)s1[(size_t)j * FDIM];
        v2[j] = (bf16)s2[(size_t)j * FDIM];
      }
      *(bf16x8*)&Ws[0][skc][sf][0] = v1;
      *(bf16x8*)&Ws[1][skc][sf][0] = v2;
    }
    __syncthreads();
    bf16x8 af[4];
#pragma unroll
    for (int mf = 0; mf < 4; ++mf)
      af[mf] = *(const bf16x8*)&As[lh][wr * 64 + mf * 16 + ll][0];
    bf16x8 b1[2], b2[2];
#pragma unroll
    for (int nf = 0; nf < 2; ++nf) {
      b1[nf] = *(const bf16x8*)&Ws[0][lh][wc * 32 + nf * 16 + ll][0];
      b2[nf] = *(const bf16x8*)&Ws[1][lh][wc * 32 + nf * 16 + ll][0];
    }
#pragma unroll
    for (int mf = 0; mf < 4; ++mf)
#pragma unroll
      for (int nf = 0; nf < 2; ++nf) {
        acc1[mf][nf] = __builtin_amdgcn_mfma_f32_16x16x32_bf16(af[mf], b1[nf], acc1[mf][nf], 0, 0, 0);
        acc2[mf][nf] = __builtin_amdgcn_mfma_f32_16x16x32_bf16(af[mf], b2[nf], acc2[mf][nf], 0, 0, 0);
      }
  }

  const int hbase = base[e] + tt * 128;
#pragma unroll
  for (int mf = 0; mf < 4; ++mf)
#pragma unroll
    for (int nf = 0; nf < 2; ++nf)
#pragma unroll
      for (int r = 0; r < 4; ++r) {
        const int rl = wr * 64 + mf * 16 + lh * 4 + r;
        if (rl < rem) {
          const int fg = ft * 64 + wc * 32 + nf * 16 + ll;
          const float a = acc1[mf][nf][r];
          const float b = acc2[mf][nf][r];
          const float h = (a / (1.f + expf(-a))) * b;
          H[(size_t)(hbase + rl) * FDIM + fg] = (bf16)h;
        }
      }
}

__global__ __launch_bounds__(256, 2) void moe_gemm2(
    const bf16* __restrict__ H, const float* __restrict__ w3,
    const int* __restrict__ tok_list, const float* __restrict__ wgt_list,
    const int* __restrict__ counts, const int* __restrict__ base,
    float* __restrict__ out)
{
  const int e = blockIdx.z;
  const int tt = blockIdx.y;
  const int dt = blockIdx.x;
  const int cnt = counts[e];
  if (tt * 128 >= cnt) return;
  int rem = cnt - tt * 128; if (rem > 128) rem = 128;

  __shared__ __align__(16) bf16 As[4][128][8];
  __shared__ __align__(16) bf16 Ws[4][64][8];
  __shared__ int toks[128];
  __shared__ float wgts[128];

  const int tid = threadIdx.x;
  const int lane = tid & 63;
  const int w = tid >> 6;
  const int wr = w >> 1, wc = w & 1;
  const int lh = lane >> 4, ll = lane & 15;

  if (tid < 128) {
    int r = tid < rem ? tid : rem - 1;
    toks[tid] = tok_list[e * T_TOK + tt * 128 + r];
    wgts[tid] = wgt_list[e * T_TOK + tt * 128 + r];
  }
  __syncthreads();

  f32x4 acc[4][2];
  const f32x4 fz = {0.f, 0.f, 0.f, 0.f};
#pragma unroll
  for (int mf = 0; mf < 4; ++mf)
#pragma unroll
    for (int nf = 0; nf < 2; ++nf) acc[mf][nf] = fz;

  const int hbase = base[e] + tt * 128;
  const float* w3e = w3 + (size_t)e * FDIM * DMODEL + dt * 64;
  const int sf = tid & 63;
  const int skc = tid >> 6;

  for (int k0 = 0; k0 < FDIM; k0 += 32) {
    __syncthreads();
#pragma unroll
    for (int i = 0; i < 2; ++i) {
      const int c = w + i * 4;
      const int kc = c >> 1;
      const int rh = c & 1;
      int row = rh * 64 + lane;
      if (row >= rem) row = rem - 1;
      GLD16(H + (size_t)(hbase + row) * FDIM + (k0 + kc * 8), &As[kc][rh * 64][0]);
    }
    {
      const size_t rowoff = (size_t)(k0 + skc * 8) * DMODEL + sf;
      const float* s3 = w3e + rowoff;
      bf16x8 v;
#pragma unroll
      for (int j = 0; j < 8; ++j) v[j] = (bf16)s3[(size_t)j * DMODEL];
      *(bf16x8*)&Ws[skc][sf][0] = v;
    }
    __syncthreads();
    bf16x8 af[4];
#pragma unroll
    for (int mf = 0; mf < 4; ++mf)
      af[mf] = *(const bf16x8*)&As[lh][wr * 64 + mf * 16 + ll][0];
    bf16x8 bv[2];
#pragma unroll
    for (int nf = 0; nf < 2; ++nf)
      bv[nf] = *(const bf16x8*)&Ws[lh][wc * 32 + nf * 16 + ll][0];
#pragma unroll
    for (int mf = 0; mf < 4; ++mf)
#pragma unroll
      for (int nf = 0; nf < 2; ++nf)
        acc[mf][nf] = __builtin_amdgcn_mfma_f32_16x16x32_bf16(af[mf], bv[nf], acc[mf][nf], 0, 0, 0);
  }

#pragma unroll
  for (int mf = 0; mf < 4; ++mf)
#pragma unroll
    for (int nf = 0; nf < 2; ++nf)
#pragma unroll
      for (int r = 0; r < 4; ++r) {
        const int rl = wr * 64 + mf * 16 + lh * 4 + r;
        if (rl < rem) {
          const int col = dt * 64 + wc * 32 + nf * 16 + ll;
          atomicAdd(&out[(size_t)toks[rl] * DMODEL + col], acc[mf][nf][r] * wgts[rl]);
        }
      }
}

extern "C" void kernel_launch(void* const* d_in, const int* in_sizes, int n_in,
                              void* d_out, int out_size, void* d_ws, size_t ws_size,
                              hipStream_t stream)
{
  const float* x  = (const float*)d_in[0];
  const float* rw = (const float*)d_in[1];
  const float* w1 = (const float*)d_in[2];
  const float* w2 = (const float*)d_in[3];
  const float* w3 = (const float*)d_in[4];
  float* out = (float*)d_out;
  char* ws = (char*)d_ws;

  // ---- blocked-path layout ----
  size_t off = 0;
  auto take = [&](size_t bytes) -> char* {
    char* p = ws + off;
    off = (off + bytes + 255) & ~(size_t)255;
    return p;
  };
  int* tok_list   = (int*)take((size_t)NEXP * T_TOK * sizeof(int));
  float* wgt_list = (float*)take((size_t)NEXP * T_TOK * sizeof(float));
  int* counts     = (int*)take(64);
  int* base       = (int*)take(64);
  int* sched      = (int*)take(MAXS * sizeof(int));
  bf16* xg        = (bf16*)take((size_t)MAXS * XG_SLOT * sizeof(bf16));   // 10.5 MiB
  bf16* hblk      = (bf16*)take((size_t)MAXS * H_SLOT * sizeof(bf16));    // 21 MiB
  bf16* w1b       = (bf16*)take((size_t)NEXP * W_SLAB * sizeof(bf16));    // 32 MiB
  bf16* w2b       = (bf16*)take((size_t)NEXP * W_SLAB * sizeof(bf16));    // 32 MiB
  bf16* w3b       = (bf16*)take((size_t)NEXP * W_SLAB * sizeof(bf16));    // 32 MiB
  const bool fast = (ws_size >= off);

  hipMemsetAsync(d_out, 0, (size_t)out_size * sizeof(float), stream);
  hipMemsetAsync(counts, 0, NEXP * sizeof(int), stream);

  if (fast) {
    moe_router<<<dim3(T_TOK), dim3(64), 0, stream>>>(x, rw, nullptr, counts, tok_list, wgt_list);
    moe_prefix<<<dim3(1), dim3(64), 0, stream>>>(counts, base, sched);
    transpose_blk12<<<dim3(FDIM / 64, DMODEL / 64, 2 * NEXP), dim3(256), 0, stream>>>(w1, w2, w1b, w2b);
    transpose_blk3<<<dim3(DMODEL / 64, FDIM / 64, NEXP), dim3(256), 0, stream>>>(w3, w3b);
    moe_gather<<<dim3(MAXS, 32), dim3(256), 0, stream>>>(x, tok_list, counts, sched, xg);
    moe_gemm1_blk<<<dim3(FDIM / 64, MAXS), dim3(256), 0, stream>>>(
        xg, w1b, w2b, counts, sched, hblk);
    moe_gemm2_blk<<<dim3(DMODEL / 128, MAXS, 2), dim3(256), 0, stream>>>(
        hblk, w3b, tok_list, wgt_list, counts, sched, out);
  } else {
    // fallback layout: xb + flat H only
    size_t foff = 0;
    auto ftake = [&](size_t bytes) -> char* {
      char* p = ws + foff;
      foff = (foff + bytes + 255) & ~(size_t)255;
      return p;
    };
    int* ftok   = (int*)ftake((size_t)NEXP * T_TOK * sizeof(int));
    float* fwgt = (float*)ftake((size_t)NEXP * T_TOK * sizeof(float));
    int* fcnt   = (int*)ftake(64);
    int* fbase  = (int*)ftake(64);
    int* fsched = (int*)ftake(MAXS * sizeof(int));
    bf16* xb    = (bf16*)ftake((size_t)T_TOK * DMODEL * sizeof(bf16));
    bf16* H     = (bf16*)ftake((size_t)2 * T_TOK * FDIM * sizeof(bf16));
    hipMemsetAsync(fcnt, 0, NEXP * sizeof(int), stream);
    moe_router<<<dim3(T_TOK), dim3(64), 0, stream>>>(x, rw, xb, fcnt, ftok, fwgt);
    moe_prefix<<<dim3(1), dim3(64), 0, stream>>>(fcnt, fbase, fsched);
    moe_gemm1<<<dim3(FDIM / 64, T_TOK / 128, NEXP), dim3(256), 0, stream>>>(
        xb, w1, w2, ftok, fcnt, fbase, H);
    moe_gemm2<<<dim3(DMODEL / 64, T_TOK / 128, NEXP), dim3(256), 0, stream>>>(
        H, w3, ftok, fwgt, fcnt, fbase, out);
  }
}